// Round 15
// baseline (227.277 us; speedup 1.0000x reference)
//
#include <hip/hip_runtime.h>
#include <hip/hip_bf16.h>

#define EMBED_DIM 4096
#define PROJ_DIM  1024
#define NROWS     8192
#define NPART     8
#define PARTSZ    128
#define MAXTILES  128
#define KSPLIT    4
#define KCHUNK    1024   // EMBED_DIM / KSPLIT
#define KSEL      256    // gathered columns per row
#define BK        32     // 64B LDS rows: bank-spread ds_read_b128

typedef __bf16 bf16x8_t __attribute__((ext_vector_type(8)));
typedef float  f32x4_t  __attribute__((ext_vector_type(4)));
typedef unsigned short ushort8_t __attribute__((ext_vector_type(8)));

__device__ __forceinline__ unsigned short f2bf(float f) {
  unsigned u = __builtin_bit_cast(unsigned, f);
  u += 0x7fffu + ((u >> 16) & 1u);   // round-to-nearest-even
  return (unsigned short)(u >> 16);
}

__device__ __forceinline__ void stage16(const void* g, void* l) {
  __builtin_amdgcn_global_load_lds(
      (const __attribute__((address_space(1))) unsigned int*)g,
      (__attribute__((address_space(3))) unsigned int*)l, 16, 0, 0);
}

// ---- Wb = bf16(W) [4096,1024]; WTb = bf16(W^T) [1024,4096] ----
__global__ __launch_bounds__(256) void prep_w(const float* __restrict__ W,
                                              unsigned short* __restrict__ Wb,
                                              unsigned short* __restrict__ WTb) {
  __shared__ float t[32][33];
  const int px = threadIdx.x & 31;
  const int ty = threadIdx.x >> 5;
  const int p0 = blockIdx.x * 32;
  const int d0 = blockIdx.y * 32;
#pragma unroll
  for (int i = 0; i < 32; i += 8) {
    float v = W[(size_t)(d0 + ty + i) * PROJ_DIM + p0 + px];
    t[ty + i][px] = v;
    Wb[(size_t)(d0 + ty + i) * PROJ_DIM + p0 + px] = f2bf(v);
  }
  __syncthreads();
#pragma unroll
  for (int i = 0; i < 32; i += 8) {
    WTb[(size_t)(p0 + ty + i) * EMBED_DIM + d0 + px] = f2bf(t[px][ty + i]);
  }
}

// ---- delta_bf16 = bf16(source - base), fully coalesced:
// one float4 per lane (16B lane stride) at two grid-stride positions;
// 4 independent coalesced VMEM streams in flight per iteration.
// n4 = NROWS*EMBED_DIM/4 = 16 * (2048 blocks * 256 thr) exactly -> no tail.
__global__ __launch_bounds__(256) void make_delta(const float4* __restrict__ b,
                                                  const float4* __restrict__ s,
                                                  ushort4* __restrict__ d, int n4) {
  const int stride = gridDim.x * blockDim.x;
  for (int i = blockIdx.x * blockDim.x + threadIdx.x; i < n4; i += 2 * stride) {
    const int j = i + stride;
    float4 b0 = b[i], s0 = s[i];
    float4 b1 = b[j], s1 = s[j];
    ushort4 o0, o1;
    o0.x = f2bf(s0.x - b0.x); o0.y = f2bf(s0.y - b0.y);
    o0.z = f2bf(s0.z - b0.z); o0.w = f2bf(s0.w - b0.w);
    o1.x = f2bf(s1.x - b1.x); o1.y = f2bf(s1.y - b1.y);
    o1.z = f2bf(s1.z - b1.z); o1.w = f2bf(s1.w - b1.w);
    d[i] = o0;
    d[j] = o1;
  }
}

// ---- single-block bucketing: hist -> scan -> tile table -> scatter ----
__global__ __launch_bounds__(1024) void k_bucket(const int* __restrict__ subs,
                                                 int* __restrict__ tiles,
                                                 int* __restrict__ n_tiles,
                                                 int* __restrict__ perm) {
  __shared__ int h[64], off[64], cur[64];
  const int t = threadIdx.x;
  if (t < 64) h[t] = 0;
  __syncthreads();
  for (int r = t; r < NROWS; r += 1024)
    atomicAdd(&h[subs[2 * r] * NPART + subs[2 * r + 1]], 1);
  __syncthreads();
  if (t < 64) {  // threads 0..63 == wave 0
    int v = h[t], incl = v;
#pragma unroll
    for (int o = 1; o < 64; o <<= 1) { int n = __shfl_up(incl, o); if (t >= o) incl += n; }
    int excl = incl - v;
    off[t] = excl; cur[t] = 0;
    int tc = (v + 127) >> 7, tincl = tc;
#pragma unroll
    for (int o = 1; o < 64; o <<= 1) { int n = __shfl_up(tincl, o); if (t >= o) tincl += n; }
    int texcl = tincl - tc;
    for (int k = 0; k < tc; ++k) {
      tiles[3 * (texcl + k) + 0] = excl + k * 128;
      tiles[3 * (texcl + k) + 1] = min(128, v - k * 128);
      tiles[3 * (texcl + k) + 2] = t;
    }
    if (t == 63) *n_tiles = tincl;
  }
  __syncthreads();
  for (int r = t; r < NROWS; r += 1024) {
    int p = subs[2 * r] * NPART + subs[2 * r + 1];
    perm[off[p] + atomicAdd(&cur[p], 1)] = r;
  }
}

// ---- GEMM1 bucketed, split-K, 2-phase dbuf, BK=32, XCD-pinned:
// each XCD owns one (col-half, K-chunk) combo -> its WTb slice (2 MB)
// stays L2-resident instead of thrashing across 8 XCDs.
//      Ypart[kz][i, 0:256] = delta[perm[i], kz*1024 .. +1024] @ Wsel ----
__global__ __launch_bounds__(256) void gemm1(
    const unsigned short* __restrict__ delta,  // [8192,4096] bf16
    const unsigned short* __restrict__ WTb,    // [1024,4096] bf16
    const int* __restrict__ perm,
    const int* __restrict__ tiles, const int* __restrict__ n_tiles,
    float* __restrict__ Ypart) {               // [KSPLIT][8192][256]
  __shared__ __attribute__((aligned(16))) __bf16 As[2][128 * BK];  // 8KB/buf
  __shared__ __attribute__((aligned(16))) __bf16 Bs[2][128 * BK];

  // XCD pinning: bid in [0,1024) -> xcd = bid&7 owns (yh, z); tile = bid>>3
  const int bid  = blockIdx.x + blockIdx.y * gridDim.x +
                   blockIdx.z * gridDim.x * gridDim.y;
  const int xcd  = bid & 7;
  const int tile = bid >> 3;           // [0,128)
  const int yh   = xcd & 1;            // col half: 0 -> s0 cols, 1 -> s1 cols
  const int z    = xcd >> 1;           // K chunk [0,4)

  if (tile >= *n_tiles) return;
  const int start = tiles[3 * tile + 0];
  const int cnt   = tiles[3 * tile + 1];
  const int bkt   = tiles[3 * tile + 2];
  const int s     = (yh == 0) ? (bkt >> 3) : (bkt & 7);
  const int kbase = z * KCHUNK;

  const int lane = threadIdx.x & 63;
  const int wave = threadIdx.x >> 6;
  const int wm   = wave >> 1;
  const int wn   = wave & 1;
  const int crow = lane >> 2;          // 0..15 row within 1KB chunk (16 rows)
  const int kel  = (lane & 3) * 8;     // k elem offset 0/8/16/24

  // 8 chunks of 16 rows per matrix; 2 chunks per wave
  const unsigned short* aptr[2];
  const unsigned short* bptr[2];
#pragma unroll
  for (int it = 0; it < 2; ++it) {
    const int c = it * 4 + wave;       // 0..7
    int rl = c * 16 + crow;
    rl = rl < cnt ? rl : 0;
    aptr[it] = delta + (size_t)perm[start + rl] * EMBED_DIM + kbase + kel;
    bptr[it] = WTb + (size_t)(s * PARTSZ + c * 16 + crow) * EMBED_DIM + kbase + kel;
  }

#define STAGE1(buf, kt)                                                \
  {                                                                    \
    _Pragma("unroll") for (int it = 0; it < 2; ++it) {                 \
      const int c = it * 4 + wave;                                     \
      stage16(aptr[it] + (kt), (char*)&As[buf][0] + c * 1024);         \
      stage16(bptr[it] + (kt), (char*)&Bs[buf][0] + c * 1024);         \
    }                                                                  \
  }

  f32x4_t acc[4][4] = {};

  STAGE1(0, 0);
  __syncthreads();
  int cur = 0;
  for (int kt = 0; kt < KCHUNK; kt += BK) {
    if (kt + BK < KCHUNK) STAGE1(cur ^ 1, kt + BK);
    bf16x8_t af[4], bv[4];
#pragma unroll
    for (int i = 0; i < 4; ++i)
      af[i] = *reinterpret_cast<const bf16x8_t*>(
          &As[cur][(wm * 64 + i * 16 + (lane & 15)) * BK + (lane >> 4) * 8]);
#pragma unroll
    for (int j = 0; j < 4; ++j)
      bv[j] = *reinterpret_cast<const bf16x8_t*>(
          &Bs[cur][(wn * 64 + j * 16 + (lane & 15)) * BK + (lane >> 4) * 8]);
    // swapped operands -> lane holds 4 consecutive output cols of one row
#pragma unroll
    for (int i = 0; i < 4; ++i)
#pragma unroll
      for (int j = 0; j < 4; ++j)
        acc[i][j] = __builtin_amdgcn_mfma_f32_16x16x32_bf16(bv[j], af[i],
                                                            acc[i][j], 0, 0, 0);
    __syncthreads();
    cur ^= 1;
  }

  float* Yo = Ypart + (size_t)z * NROWS * KSEL;
#pragma unroll
  for (int i = 0; i < 4; ++i) {
    const int row_local = wm * 64 + i * 16 + (lane & 15);
    if (row_local < cnt) {
#pragma unroll
      for (int j = 0; j < 4; ++j) {
        const int col = yh * 128 + wn * 64 + j * 16 + (lane >> 4) * 4;
        *reinterpret_cast<f32x4_t*>(&Yo[(size_t)(start + row_local) * KSEL + col]) =
            acc[i][j];
      }
    }
  }
}

// ---- combine split-K partials -> Ysel bf16 [8192, 256] ----
__global__ __launch_bounds__(256) void combine(const float* __restrict__ Yp,
                                               unsigned short* __restrict__ Ysel) {
  const int total = NROWS * KSEL / 4;
  const size_t stride = (size_t)NROWS * KSEL;
  for (int i = blockIdx.x * blockDim.x + threadIdx.x; i < total;
       i += gridDim.x * blockDim.x) {
    float4 s = ((const float4*)Yp)[i];
#pragma unroll
    for (int z = 1; z < KSPLIT; ++z) {
      float4 v = ((const float4*)(Yp + stride * z))[i];
      s.x += v.x; s.y += v.y; s.z += v.z; s.w += v.w;
    }
    ushort4 o;
    o.x = f2bf(s.x); o.y = f2bf(s.y); o.z = f2bf(s.z); o.w = f2bf(s.w);
    ((ushort4*)Ysel)[i] = o;
  }
}

// ---- GEMM2: 512 threads, tile 128 rows x 256 cols, BK=32, 2-phase dbuf,
// XCD-pinned: each XCD owns 2 of the 16 column panels -> its Wb slice
// (1 MB) stays L2-resident. Round-11 proven schedule otherwise.
// out[perm[i],:] = base[perm[i],:] + Ysel[i,:] @ Wsel^T ----
__global__ __launch_bounds__(512) void gemm2(
    const unsigned short* __restrict__ Ysel,   // [8192, 256] bf16
    const unsigned short* __restrict__ Wb,     // [4096,1024] bf16
    const int* __restrict__ perm,
    const int* __restrict__ tiles, const int* __restrict__ n_tiles,
    const float* __restrict__ base, float* __restrict__ out) {
  __shared__ __attribute__((aligned(16))) __bf16 As[2][128 * BK];  // 8KB/buf
  __shared__ __attribute__((aligned(16))) __bf16 Bs[2][256 * BK];  // 16KB/buf

  // XCD pinning: bid in [0,2048) -> xcd = bid&7; j = bid>>3 in [0,256);
  // tile walks fastest (shares the XCD's pinned Wb panel), panel = xcd*2+(j>>7)
  const int bid  = blockIdx.x + blockIdx.y * gridDim.x;
  const int xcd  = bid & 7;
  const int j_   = bid >> 3;           // [0,256)
  const int tile = j_ & 127;
  const int npnl = xcd * 2 + (j_ >> 7);  // [0,16)

  if (tile >= *n_tiles) return;
  const int start = tiles[3 * tile + 0];
  const int cnt   = tiles[3 * tile + 1];
  const int bkt   = tiles[3 * tile + 2];
  const int s0    = bkt >> 3, s1 = bkt & 7;
  const int n0    = npnl * 256;

  const int tid  = threadIdx.x;        // 0..511
  const int lane = tid & 63;
  const int wave = tid >> 6;           // 0..7
  const int wm   = wave >> 2;          // 0..1
  const int wn   = wave & 3;           // 0..3

  // A stage: 512 slots = 128 rows x 4 k-groups of 8; 1 load/thread
  const int arow = tid >> 2;           // 0..127
  const int akel = (tid & 3) * 8;
  const int arc  = arow < cnt ? arow : 0;
  const unsigned short* aptr = Ysel + (size_t)(start + arc) * KSEL + akel;

  // B stage: 1024 slots = 256 rows x 4 k-groups; 2 loads/thread
  const unsigned short* bptr[2];
#pragma unroll
  for (int q = 0; q < 2; ++q) {
    const int sidx = q * 512 + tid;
    const int brow = sidx >> 2;        // 0..255
    bptr[q] = Wb + (size_t)(n0 + brow) * PROJ_DIM + (sidx & 3) * 8;
  }

#define STAGE2(buf, kt)                                                        \
  {                                                                            \
    const int sp   = ((kt) < 128) ? s0 : s1;                                   \
    const int coff = sp * PARTSZ + ((kt) & 127);                               \
    stage16(aptr + (kt), (char*)&As[buf][0] + tid * 16);                       \
    stage16(bptr[0] + coff, (char*)&Bs[buf][0] + tid * 16);                    \
    stage16(bptr[1] + coff, (char*)&Bs[buf][0] + 8192 + tid * 16);             \
  }

  f32x4_t acc[4][4] = {};

  STAGE2(0, 0);
  __syncthreads();
  int cur = 0;
#pragma unroll
  for (int kt = 0; kt < KSEL; kt += BK) {
    if (kt + BK < KSEL) STAGE2(cur ^ 1, kt + BK);
    bf16x8_t af[4], bv[4];
#pragma unroll
    for (int i = 0; i < 4; ++i)
      af[i] = *reinterpret_cast<const bf16x8_t*>(
          &As[cur][(wm * 64 + i * 16 + (lane & 15)) * BK + (lane >> 4) * 8]);
#pragma unroll
    for (int j = 0; j < 4; ++j)
      bv[j] = *reinterpret_cast<const bf16x8_t*>(
          &Bs[cur][(wn * 64 + j * 16 + (lane & 15)) * BK + (lane >> 4) * 8]);
    // swapped operands -> lane holds 4 consecutive output cols of one row
#pragma unroll
    for (int i = 0; i < 4; ++i)
#pragma unroll
      for (int j = 0; j < 4; ++j)
        acc[i][j] = __builtin_amdgcn_mfma_f32_16x16x32_bf16(bv[j], af[i],
                                                            acc[i][j], 0, 0, 0);
    __syncthreads();
    cur ^= 1;
  }

#pragma unroll
  for (int i = 0; i < 4; ++i) {
    const int row_local = wm * 64 + i * 16 + (lane & 15);
    if (row_local < cnt) {
      const int grow = perm[start + row_local];
#pragma unroll
      for (int j = 0; j < 4; ++j) {
        const int col = n0 + wn * 64 + j * 16 + (lane >> 4) * 4;
        const size_t o = (size_t)grow * EMBED_DIM + col;
        f32x4_t b4 = *reinterpret_cast<const f32x4_t*>(&base[o]);
        *reinterpret_cast<f32x4_t*>(&out[o]) = acc[i][j] + b4;
      }
    }
  }
}

extern "C" void kernel_launch(void* const* d_in, const int* in_sizes, int n_in,
                              void* d_out, int out_size, void* d_ws, size_t ws_size,
                              hipStream_t stream) {
  const float* base   = (const float*)d_in[0];
  const float* source = (const float*)d_in[1];
  const int*   subs   = (const int*)d_in[2];
  const float* W      = (const float*)d_in[3];
  float* out = (float*)d_out;

  // d_out scratch (dead before gemm2 writes out):
  //   delta bf16 [8192,4096] @ 0        (64 MB)
  //   Ypart f32 [4][8192][256] @ 64 MB  (32 MB)
  unsigned short* delta = (unsigned short*)d_out;
  float* Ypart = (float*)((char*)d_out + (64u << 20));

  // ws: Wb 8MB | WTb 8MB | Ysel 4MB | meta
  char* ws = (char*)d_ws;
  unsigned short* Wb   = (unsigned short*)(ws);
  unsigned short* WTb  = (unsigned short*)(ws + (8u << 20));
  unsigned short* Ysel = (unsigned short*)(ws + (16u << 20));
  char* meta = ws + (21u << 20);
  int* n_tiles = (int*)(meta);
  int* tiles   = (int*)(meta + 256);   // 128*3 ints
  int* perm    = (int*)(meta + 4096);  // 8192 ints

  k_bucket<<<1, 1024, 0, stream>>>(subs, tiles, n_tiles, perm);

  prep_w<<<dim3(PROJ_DIM / 32, EMBED_DIM / 32), 256, 0, stream>>>(W, Wb, WTb);

  const int n4 = NROWS * EMBED_DIM / 4;
  make_delta<<<2048, 256, 0, stream>>>((const float4*)base, (const float4*)source,
                                       (ushort4*)delta, n4);

  gemm1<<<dim3(MAXTILES, 2, KSPLIT), 256, 0, stream>>>(delta, WTb, perm, tiles,
                                                       n_tiles, Ypart);
  combine<<<1024, 256, 0, stream>>>(Ypart, Ysel);

  gemm2<<<dim3(MAXTILES, EMBED_DIM / 256), 512, 0, stream>>>(Ysel, Wb, perm, tiles,
                                                             n_tiles, base, out);
}

// Round 16
// 215.758 us; speedup vs baseline: 1.0534x; 1.0534x over previous
//
#include <hip/hip_runtime.h>
#include <hip/hip_bf16.h>

#define EMBED_DIM 4096
#define PROJ_DIM  1024
#define NROWS     8192
#define NPART     8
#define PARTSZ    128
#define MAXTILES  128
#define KSPLIT    8
#define KCHUNK    512    // EMBED_DIM / KSPLIT
#define KSEL      256    // gathered columns per row
#define BK        32     // 64B LDS rows: bank-spread ds_read_b128

typedef __bf16 bf16x8_t __attribute__((ext_vector_type(8)));
typedef float  f32x4_t  __attribute__((ext_vector_type(4)));
typedef unsigned short ushort8_t __attribute__((ext_vector_type(8)));

__device__ __forceinline__ unsigned short f2bf(float f) {
  unsigned u = __builtin_bit_cast(unsigned, f);
  u += 0x7fffu + ((u >> 16) & 1u);   // round-to-nearest-even
  return (unsigned short)(u >> 16);
}

__device__ __forceinline__ void stage16(const void* g, void* l) {
  __builtin_amdgcn_global_load_lds(
      (const __attribute__((address_space(1))) unsigned int*)g,
      (__attribute__((address_space(3))) unsigned int*)l, 16, 0, 0);
}

// ---- Wb = bf16(W) [4096,1024]; WTb = bf16(W^T) [1024,4096] ----
__global__ __launch_bounds__(256) void prep_w(const float* __restrict__ W,
                                              unsigned short* __restrict__ Wb,
                                              unsigned short* __restrict__ WTb) {
  __shared__ float t[32][33];
  const int px = threadIdx.x & 31;
  const int ty = threadIdx.x >> 5;
  const int p0 = blockIdx.x * 32;
  const int d0 = blockIdx.y * 32;
#pragma unroll
  for (int i = 0; i < 32; i += 8) {
    float v = W[(size_t)(d0 + ty + i) * PROJ_DIM + p0 + px];
    t[ty + i][px] = v;
    Wb[(size_t)(d0 + ty + i) * PROJ_DIM + p0 + px] = f2bf(v);
  }
  __syncthreads();
#pragma unroll
  for (int i = 0; i < 32; i += 8) {
    WTb[(size_t)(p0 + ty + i) * EMBED_DIM + d0 + px] = f2bf(t[px][ty + i]);
  }
}

// ---- single-block bucketing: hist -> scan -> tile table -> scatter ----
__global__ __launch_bounds__(1024) void k_bucket(const int* __restrict__ subs,
                                                 int* __restrict__ tiles,
                                                 int* __restrict__ n_tiles,
                                                 int* __restrict__ perm) {
  __shared__ int h[64], off[64], cur[64];
  const int t = threadIdx.x;
  if (t < 64) h[t] = 0;
  __syncthreads();
  for (int r = t; r < NROWS; r += 1024)
    atomicAdd(&h[subs[2 * r] * NPART + subs[2 * r + 1]], 1);
  __syncthreads();
  if (t < 64) {  // threads 0..63 == wave 0
    int v = h[t], incl = v;
#pragma unroll
    for (int o = 1; o < 64; o <<= 1) { int n = __shfl_up(incl, o); if (t >= o) incl += n; }
    int excl = incl - v;
    off[t] = excl; cur[t] = 0;
    int tc = (v + 127) >> 7, tincl = tc;
#pragma unroll
    for (int o = 1; o < 64; o <<= 1) { int n = __shfl_up(tincl, o); if (t >= o) tincl += n; }
    int texcl = tincl - tc;
    for (int k = 0; k < tc; ++k) {
      tiles[3 * (texcl + k) + 0] = excl + k * 128;
      tiles[3 * (texcl + k) + 1] = min(128, v - k * 128);
      tiles[3 * (texcl + k) + 2] = t;
    }
    if (t == 63) *n_tiles = tincl;
  }
  __syncthreads();
  for (int r = t; r < NROWS; r += 1024) {
    int p = subs[2 * r] * NPART + subs[2 * r + 1];
    perm[off[p] + atomicAdd(&cur[p], 1)] = r;
  }
}

// ---- GEMM1 fused (delta in-register), XCD-pinned, T14 async-stage split.
// Block: 256 thr, 4 waves (1m x 4n). Tile: BM=64 rows x BN=256 cols x K=512.
// Pinning: z = bid&7 (one K-chunk per XCD -> WTb slice 1MB L2-resident).
// T14: issue base/source loads -> COMPUTE (hides HBM latency) -> cvt+ds_write.
// Ypart[z][i, 0:256] = (source-base)[perm[i], z*512 .. +512] @ Wsel ----
__global__ __launch_bounds__(256) void gemm1(
    const float* __restrict__ base, const float* __restrict__ source,
    const unsigned short* __restrict__ WTb,    // [1024,4096] bf16
    const int* __restrict__ perm,
    const int* __restrict__ tiles, const int* __restrict__ n_tiles,
    float* __restrict__ Ypart) {               // [KSPLIT][8192][256]
  __shared__ __attribute__((aligned(16))) __bf16 As[2][64 * BK];    // 4KB/buf
  __shared__ __attribute__((aligned(16))) __bf16 Bs[2][256 * BK];   // 16KB/buf

  const int bid  = blockIdx.x;         // [0,2048)
  const int z    = bid & 7;            // XCD-pinned K chunk
  const int th   = bid >> 3;           // [0,256)
  const int tile = th & 127;
  const int half = th >> 7;            // 0/1: which 64-row half of the tile
  if (tile >= *n_tiles) return;
  const int start = tiles[3 * tile + 0];
  const int cnt   = tiles[3 * tile + 1];
  if (half * 64 >= cnt) return;
  const int bkt   = tiles[3 * tile + 2];
  const int s0    = bkt >> 3, s1 = bkt & 7;
  const int kbase = z * KCHUNK;

  const int tid  = threadIdx.x;
  const int lane = tid & 63;
  const int wave = tid >> 6;           // 0..3 == column quarter (wm = 0)

  // A reg-stage slot: 64 rows x 4 k-groups of 8 = 256 slots, 1/thread
  const int at_row = tid >> 2;         // 0..63
  const int at_kg  = (tid & 3) * 8;    // 0/8/16/24
  const int arow_g = perm[start + min(half * 64 + at_row, cnt - 1)];
  const float* abase = base   + (size_t)arow_g * EMBED_DIM + kbase + at_kg;
  const float* asrc  = source + (size_t)arow_g * EMBED_DIM + kbase + at_kg;

  // B stage: 16 chunks of 16 rows (256 selected W-cols); 4 stage16/thread
  const unsigned short* bptr[4];
#pragma unroll
  for (int it = 0; it < 4; ++it) {
    const int r   = (it * 4 + wave) * 16 + (lane >> 2);   // 0..255
    const int sel = (r < 128) ? (s0 * PARTSZ + r) : (s1 * PARTSZ + r - 128);
    bptr[it] = WTb + (size_t)sel * EMBED_DIM + kbase + (lane & 3) * 8;
  }

  float4 ab0, ab1, as0, as1;  // in-flight base/source (T14 split)

#define ALOAD(kt)                                                           \
  {                                                                         \
    ab0 = *(const float4*)(abase + (kt));                                   \
    ab1 = *(const float4*)(abase + (kt) + 4);                               \
    as0 = *(const float4*)(asrc + (kt));                                    \
    as1 = *(const float4*)(asrc + (kt) + 4);                                \
  }

#define ASTORE(buf)                                                         \
  {                                                                         \
    ushort8_t o;                                                            \
    o[0] = f2bf(as0.x - ab0.x); o[1] = f2bf(as0.y - ab0.y);                 \
    o[2] = f2bf(as0.z - ab0.z); o[3] = f2bf(as0.w - ab0.w);                 \
    o[4] = f2bf(as1.x - ab1.x); o[5] = f2bf(as1.y - ab1.y);                 \
    o[6] = f2bf(as1.z - ab1.z); o[7] = f2bf(as1.w - ab1.w);                 \
    *(ushort8_t*)&As[buf][at_row * BK + at_kg] = o;                         \
  }

#define BSTAGE(buf, kt)                                                     \
  {                                                                         \
    _Pragma("unroll") for (int it = 0; it < 4; ++it) {                      \
      const int c = it * 4 + wave;                                          \
      stage16(bptr[it] + (kt), (char*)&Bs[buf][0] + c * 1024);              \
    }                                                                       \
  }

#define COMPUTE1(buf)                                                       \
  {                                                                         \
    bf16x8_t af[4], bv[4];                                                  \
    _Pragma("unroll") for (int i = 0; i < 4; ++i)                           \
      af[i] = *reinterpret_cast<const bf16x8_t*>(                           \
          &As[buf][(i * 16 + (lane & 15)) * BK + (lane >> 4) * 8]);         \
    _Pragma("unroll") for (int j = 0; j < 4; ++j)                           \
      bv[j] = *reinterpret_cast<const bf16x8_t*>(                           \
          &Bs[buf][(wave * 64 + j * 16 + (lane & 15)) * BK + (lane >> 4) * 8]); \
    _Pragma("unroll") for (int i = 0; i < 4; ++i)                           \
      _Pragma("unroll") for (int j = 0; j < 4; ++j)                         \
        acc[i][j] = __builtin_amdgcn_mfma_f32_16x16x32_bf16(bv[j], af[i],   \
                                                            acc[i][j], 0, 0, 0); \
  }

  f32x4_t acc[4][4] = {};

  // prologue: stage chunk 0 (A latency exposed once)
  ALOAD(0);
  BSTAGE(0, 0);
  ASTORE(0);
  __syncthreads();
  int cur = 0;
  for (int kt = 0; kt < KCHUNK; kt += BK) {
    const bool more = (kt + BK < KCHUNK);
    if (more) {
      ALOAD(kt + BK);           // issue HBM loads...
      BSTAGE(cur ^ 1, kt + BK); // ...and L2 B-staging
    }
    COMPUTE1(cur);              // MFMAs hide the A-load latency
    if (more) ASTORE(cur ^ 1);  // vmcnt wait lands here, after compute
    __syncthreads();
    cur ^= 1;
  }

  float* Yo = Ypart + (size_t)z * NROWS * KSEL;
#pragma unroll
  for (int i = 0; i < 4; ++i) {
    const int row_local = half * 64 + i * 16 + (lane & 15);
    if (row_local < cnt) {
#pragma unroll
      for (int j = 0; j < 4; ++j) {
        const int col = wave * 64 + j * 16 + (lane >> 4) * 4;
        *reinterpret_cast<f32x4_t*>(&Yo[(size_t)(start + row_local) * KSEL + col]) =
            acc[i][j];
      }
    }
  }
}

// ---- combine split-K partials (8) -> Ysel bf16 [8192, 256] ----
__global__ __launch_bounds__(256) void combine(const float* __restrict__ Yp,
                                               unsigned short* __restrict__ Ysel) {
  const int total = NROWS * KSEL / 4;
  const size_t stride = (size_t)NROWS * KSEL;
  for (int i = blockIdx.x * blockDim.x + threadIdx.x; i < total;
       i += gridDim.x * blockDim.x) {
    float4 s = ((const float4*)Yp)[i];
#pragma unroll
    for (int z = 1; z < KSPLIT; ++z) {
      float4 v = ((const float4*)(Yp + stride * z))[i];
      s.x += v.x; s.y += v.y; s.z += v.z; s.w += v.w;
    }
    ushort4 o;
    o.x = f2bf(s.x); o.y = f2bf(s.y); o.z = f2bf(s.z); o.w = f2bf(s.w);
    ((ushort4*)Ysel)[i] = o;
  }
}

// ---- GEMM2: 512 threads, tile 128 rows x 256 cols, BK=32, 2-phase dbuf,
// XCD-pinned (round-15 proven, byte-identical).
// out[perm[i],:] = base[perm[i],:] + Ysel[i,:] @ Wsel^T ----
__global__ __launch_bounds__(512) void gemm2(
    const unsigned short* __restrict__ Ysel,   // [8192, 256] bf16
    const unsigned short* __restrict__ Wb,     // [4096,1024] bf16
    const int* __restrict__ perm,
    const int* __restrict__ tiles, const int* __restrict__ n_tiles,
    const float* __restrict__ base, float* __restrict__ out) {
  __shared__ __attribute__((aligned(16))) __bf16 As[2][128 * BK];  // 8KB/buf
  __shared__ __attribute__((aligned(16))) __bf16 Bs[2][256 * BK];  // 16KB/buf

  const int bid  = blockIdx.x + blockIdx.y * gridDim.x;
  const int xcd  = bid & 7;
  const int j_   = bid >> 3;           // [0,256)
  const int tile = j_ & 127;
  const int npnl = xcd * 2 + (j_ >> 7);  // [0,16)

  if (tile >= *n_tiles) return;
  const int start = tiles[3 * tile + 0];
  const int cnt   = tiles[3 * tile + 1];
  const int bkt   = tiles[3 * tile + 2];
  const int s0    = bkt >> 3, s1 = bkt & 7;
  const int n0    = npnl * 256;

  const int tid  = threadIdx.x;        // 0..511
  const int lane = tid & 63;
  const int wave = tid >> 6;           // 0..7
  const int wm   = wave >> 2;          // 0..1
  const int wn   = wave & 3;           // 0..3

  const int arow = tid >> 2;           // 0..127
  const int akel = (tid & 3) * 8;
  const int arc  = arow < cnt ? arow : 0;
  const unsigned short* aptr = Ysel + (size_t)(start + arc) * KSEL + akel;

  const unsigned short* bptr[2];
#pragma unroll
  for (int q = 0; q < 2; ++q) {
    const int sidx = q * 512 + tid;
    const int brow = sidx >> 2;        // 0..255
    bptr[q] = Wb + (size_t)(n0 + brow) * PROJ_DIM + (sidx & 3) * 8;
  }

#define STAGE2(buf, kt)                                                        \
  {                                                                            \
    const int sp   = ((kt) < 128) ? s0 : s1;                                   \
    const int coff = sp * PARTSZ + ((kt) & 127);                               \
    stage16(aptr + (kt), (char*)&As[buf][0] + tid * 16);                       \
    stage16(bptr[0] + coff, (char*)&Bs[buf][0] + tid * 16);                    \
    stage16(bptr[1] + coff, (char*)&Bs[buf][0] + 8192 + tid * 16);             \
  }

  f32x4_t acc[4][4] = {};

  STAGE2(0, 0);
  __syncthreads();
  int cur = 0;
#pragma unroll
  for (int kt = 0; kt < KSEL; kt += BK) {
    if (kt + BK < KSEL) STAGE2(cur ^ 1, kt + BK);
    bf16x8_t af[4], bv[4];
#pragma unroll
    for (int i = 0; i < 4; ++i)
      af[i] = *reinterpret_cast<const bf16x8_t*>(
          &As[cur][(wm * 64 + i * 16 + (lane & 15)) * BK + (lane >> 4) * 8]);
#pragma unroll
    for (int j = 0; j < 4; ++j)
      bv[j] = *reinterpret_cast<const bf16x8_t*>(
          &Bs[cur][(wn * 64 + j * 16 + (lane & 15)) * BK + (lane >> 4) * 8]);
    // swapped operands -> lane holds 4 consecutive output cols of one row
#pragma unroll
    for (int i = 0; i < 4; ++i)
#pragma unroll
      for (int j = 0; j < 4; ++j)
        acc[i][j] = __builtin_amdgcn_mfma_f32_16x16x32_bf16(bv[j], af[i],
                                                            acc[i][j], 0, 0, 0);
    __syncthreads();
    cur ^= 1;
  }

#pragma unroll
  for (int i = 0; i < 4; ++i) {
    const int row_local = wm * 64 + i * 16 + (lane & 15);
    if (row_local < cnt) {
      const int grow = perm[start + row_local];
#pragma unroll
      for (int j = 0; j < 4; ++j) {
        const int col = n0 + wn * 64 + j * 16 + (lane >> 4) * 4;
        const size_t o = (size_t)grow * EMBED_DIM + col;
        f32x4_t b4 = *reinterpret_cast<const f32x4_t*>(&base[o]);
        *reinterpret_cast<f32x4_t*>(&out[o]) = acc[i][j] + b4;
      }
    }
  }
}

extern "C" void kernel_launch(void* const* d_in, const int* in_sizes, int n_in,
                              void* d_out, int out_size, void* d_ws, size_t ws_size,
                              hipStream_t stream) {
  const float* base   = (const float*)d_in[0];
  const float* source = (const float*)d_in[1];
  const int*   subs   = (const int*)d_in[2];
  const float* W      = (const float*)d_in[3];
  float* out = (float*)d_out;

  // d_out scratch (dead before gemm2 writes out):
  //   Ypart f32 [8][8192][256] @ 0   (64 MB; d_out is 128 MB)
  float* Ypart = (float*)d_out;

  // ws: Wb 8MB | WTb 8MB | Ysel 4MB | meta
  char* ws = (char*)d_ws;
  unsigned short* Wb   = (unsigned short*)(ws);
  unsigned short* WTb  = (unsigned short*)(ws + (8u << 20));
  unsigned short* Ysel = (unsigned short*)(ws + (16u << 20));
  char* meta = ws + (21u << 20);
  int* n_tiles = (int*)(meta);
  int* tiles   = (int*)(meta + 256);   // 128*3 ints
  int* perm    = (int*)(meta + 4096);  // 8192 ints

  k_bucket<<<1, 1024, 0, stream>>>(subs, tiles, n_tiles, perm);

  prep_w<<<dim3(PROJ_DIM / 32, EMBED_DIM / 32), 256, 0, stream>>>(W, Wb, WTb);

  gemm1<<<MAXTILES * 2 * KSPLIT, 256, 0, stream>>>(base, source, WTb, perm,
                                                   tiles, n_tiles, Ypart);
  combine<<<1024, 256, 0, stream>>>(Ypart, Ysel);

  gemm2<<<dim3(MAXTILES, EMBED_DIM / 256), 512, 0, stream>>>(Ysel, Wb, perm, tiles,
                                                             n_tiles, base, out);
}

// Round 17
// 214.980 us; speedup vs baseline: 1.0572x; 1.0036x over previous
//
#include <hip/hip_runtime.h>
#include <hip/hip_bf16.h>

#define EMBED_DIM 4096
#define PROJ_DIM  1024
#define NROWS     8192
#define NPART     8
#define PARTSZ    128
#define MAXTILES  128
#define KSPLIT    8
#define KCHUNK    512    // EMBED_DIM / KSPLIT
#define KSEL      256    // gathered columns per row
#define BK        32     // 64B LDS rows: bank-spread ds_read_b128
#define NJ        16     // K-steps per block in gemm1 (KCHUNK/BK)

typedef __bf16 bf16x8_t __attribute__((ext_vector_type(8)));
typedef float  f32x4_t  __attribute__((ext_vector_type(4)));
typedef unsigned short ushort8_t __attribute__((ext_vector_type(8)));

__device__ __forceinline__ unsigned short f2bf(float f) {
  unsigned u = __builtin_bit_cast(unsigned, f);
  u += 0x7fffu + ((u >> 16) & 1u);   // round-to-nearest-even
  return (unsigned short)(u >> 16);
}

__device__ __forceinline__ void stage16(const void* g, void* l) {
  __builtin_amdgcn_global_load_lds(
      (const __attribute__((address_space(1))) unsigned int*)g,
      (__attribute__((address_space(3))) unsigned int*)l, 16, 0, 0);
}

// ---- Wb = bf16(W) [4096,1024]; WTb = bf16(W^T) [1024,4096] ----
__global__ __launch_bounds__(256) void prep_w(const float* __restrict__ W,
                                              unsigned short* __restrict__ Wb,
                                              unsigned short* __restrict__ WTb) {
  __shared__ float t[32][33];
  const int px = threadIdx.x & 31;
  const int ty = threadIdx.x >> 5;
  const int p0 = blockIdx.x * 32;
  const int d0 = blockIdx.y * 32;
#pragma unroll
  for (int i = 0; i < 32; i += 8) {
    float v = W[(size_t)(d0 + ty + i) * PROJ_DIM + p0 + px];
    t[ty + i][px] = v;
    Wb[(size_t)(d0 + ty + i) * PROJ_DIM + p0 + px] = f2bf(v);
  }
  __syncthreads();
#pragma unroll
  for (int i = 0; i < 32; i += 8) {
    WTb[(size_t)(p0 + ty + i) * EMBED_DIM + d0 + px] = f2bf(t[px][ty + i]);
  }
}

// ---- single-block bucketing: hist -> scan -> tile table -> scatter ----
__global__ __launch_bounds__(1024) void k_bucket(const int* __restrict__ subs,
                                                 int* __restrict__ tiles,
                                                 int* __restrict__ n_tiles,
                                                 int* __restrict__ perm) {
  __shared__ int h[64], off[64], cur[64];
  const int t = threadIdx.x;
  if (t < 64) h[t] = 0;
  __syncthreads();
  for (int r = t; r < NROWS; r += 1024)
    atomicAdd(&h[subs[2 * r] * NPART + subs[2 * r + 1]], 1);
  __syncthreads();
  if (t < 64) {  // threads 0..63 == wave 0
    int v = h[t], incl = v;
#pragma unroll
    for (int o = 1; o < 64; o <<= 1) { int n = __shfl_up(incl, o); if (t >= o) incl += n; }
    int excl = incl - v;
    off[t] = excl; cur[t] = 0;
    int tc = (v + 127) >> 7, tincl = tc;
#pragma unroll
    for (int o = 1; o < 64; o <<= 1) { int n = __shfl_up(tincl, o); if (t >= o) tincl += n; }
    int texcl = tincl - tc;
    for (int k = 0; k < tc; ++k) {
      tiles[3 * (texcl + k) + 0] = excl + k * 128;
      tiles[3 * (texcl + k) + 1] = min(128, v - k * 128);
      tiles[3 * (texcl + k) + 2] = t;
    }
    if (t == 63) *n_tiles = tincl;
  }
  __syncthreads();
  for (int r = t; r < NROWS; r += 1024) {
    int p = subs[2 * r] * NPART + subs[2 * r + 1];
    perm[off[p] + atomicAdd(&cur[p], 1)] = r;
  }
}

// ---- GEMM1 fused (delta in-register), XCD-pinned, depth-2 A prefetch.
// Set A holds even chunks, set B odd chunks; chunk j+2 is issued at iter j
// and consumed at iter j+1 -> HBM latency window = full iteration + compute.
// BSTAGE issued BEFORE ALOAD so the barrier's vmcnt wait (staging done) can
// leave the newer A-loads in flight across the barrier.
// Ypart[z][i, 0:256] = (source-base)[perm[i], z*512 .. +512] @ Wsel ----
__global__ __launch_bounds__(256) void gemm1(
    const float* __restrict__ base, const float* __restrict__ source,
    const unsigned short* __restrict__ WTb,    // [1024,4096] bf16
    const int* __restrict__ perm,
    const int* __restrict__ tiles, const int* __restrict__ n_tiles,
    float* __restrict__ Ypart) {               // [KSPLIT][8192][256]
  __shared__ __attribute__((aligned(16))) __bf16 As[2][64 * BK];    // 4KB/buf
  __shared__ __attribute__((aligned(16))) __bf16 Bs[2][256 * BK];   // 16KB/buf

  const int bid  = blockIdx.x;         // [0,2048)
  const int z    = bid & 7;            // XCD-pinned K chunk
  const int th   = bid >> 3;           // [0,256)
  const int tile = th & 127;
  const int half = th >> 7;            // 0/1: which 64-row half of the tile
  if (tile >= *n_tiles) return;
  const int start = tiles[3 * tile + 0];
  const int cnt   = tiles[3 * tile + 1];
  if (half * 64 >= cnt) return;
  const int bkt   = tiles[3 * tile + 2];
  const int s0    = bkt >> 3, s1 = bkt & 7;
  const int kbase = z * KCHUNK;

  const int tid  = threadIdx.x;
  const int lane = tid & 63;
  const int wave = tid >> 6;           // 0..3 == column quarter (wm = 0)

  // A reg-stage slot: 64 rows x 4 k-groups of 8 = 256 slots, 1/thread
  const int at_row = tid >> 2;         // 0..63
  const int at_kg  = (tid & 3) * 8;    // 0/8/16/24
  const int arow_g = perm[start + min(half * 64 + at_row, cnt - 1)];
  const float* abase = base   + (size_t)arow_g * EMBED_DIM + kbase + at_kg;
  const float* asrc  = source + (size_t)arow_g * EMBED_DIM + kbase + at_kg;

  // B stage: 16 chunks of 16 rows (256 selected W-cols); 4 stage16/thread
  const unsigned short* bptr[4];
#pragma unroll
  for (int it = 0; it < 4; ++it) {
    const int r   = (it * 4 + wave) * 16 + (lane >> 2);   // 0..255
    const int sel = (r < 128) ? (s0 * PARTSZ + r) : (s1 * PARTSZ + r - 128);
    bptr[it] = WTb + (size_t)sel * EMBED_DIM + kbase + (lane & 3) * 8;
  }

  // two named register sets (depth-2 pipeline): A = even chunks, B = odd
  float4 abA0, abA1, asA0, asA1;
  float4 abB0, abB1, asB0, asB1;

#define ALOADA(kt)                                                          \
  { abA0 = *(const float4*)(abase + (kt));                                  \
    abA1 = *(const float4*)(abase + (kt) + 4);                              \
    asA0 = *(const float4*)(asrc + (kt));                                   \
    asA1 = *(const float4*)(asrc + (kt) + 4); }

#define ALOADB(kt)                                                          \
  { abB0 = *(const float4*)(abase + (kt));                                  \
    abB1 = *(const float4*)(abase + (kt) + 4);                              \
    asB0 = *(const float4*)(asrc + (kt));                                   \
    asB1 = *(const float4*)(asrc + (kt) + 4); }

#define ASTOREA(buf)                                                        \
  { ushort8_t o;                                                            \
    o[0] = f2bf(asA0.x - abA0.x); o[1] = f2bf(asA0.y - abA0.y);             \
    o[2] = f2bf(asA0.z - abA0.z); o[3] = f2bf(asA0.w - abA0.w);             \
    o[4] = f2bf(asA1.x - abA1.x); o[5] = f2bf(asA1.y - abA1.y);             \
    o[6] = f2bf(asA1.z - abA1.z); o[7] = f2bf(asA1.w - abA1.w);             \
    *(ushort8_t*)&As[buf][at_row * BK + at_kg] = o; }

#define ASTOREB(buf)                                                        \
  { ushort8_t o;                                                            \
    o[0] = f2bf(asB0.x - abB0.x); o[1] = f2bf(asB0.y - abB0.y);             \
    o[2] = f2bf(asB0.z - abB0.z); o[3] = f2bf(asB0.w - abB0.w);             \
    o[4] = f2bf(asB1.x - abB1.x); o[5] = f2bf(asB1.y - abB1.y);             \
    o[6] = f2bf(asB1.z - abB1.z); o[7] = f2bf(asB1.w - abB1.w);             \
    *(ushort8_t*)&As[buf][at_row * BK + at_kg] = o; }

#define BSTAGE(buf, kt)                                                     \
  {                                                                         \
    _Pragma("unroll") for (int it = 0; it < 4; ++it) {                      \
      const int c = it * 4 + wave;                                          \
      stage16(bptr[it] + (kt), (char*)&Bs[buf][0] + c * 1024);              \
    }                                                                       \
  }

#define COMPUTE1(buf)                                                       \
  {                                                                         \
    bf16x8_t af[4], bv[4];                                                  \
    _Pragma("unroll") for (int i = 0; i < 4; ++i)                           \
      af[i] = *reinterpret_cast<const bf16x8_t*>(                           \
          &As[buf][(i * 16 + (lane & 15)) * BK + (lane >> 4) * 8]);         \
    _Pragma("unroll") for (int j = 0; j < 4; ++j)                           \
      bv[j] = *reinterpret_cast<const bf16x8_t*>(                           \
          &Bs[buf][(wave * 64 + j * 16 + (lane & 15)) * BK + (lane >> 4) * 8]); \
    _Pragma("unroll") for (int i = 0; i < 4; ++i)                           \
      _Pragma("unroll") for (int j = 0; j < 4; ++j)                         \
        acc[i][j] = __builtin_amdgcn_mfma_f32_16x16x32_bf16(bv[j], af[i],   \
                                                            acc[i][j], 0, 0, 0); \
  }

  f32x4_t acc[4][4] = {};

  // prologue: chunk0 -> As[0] (latency exposed once); chunk1 loads in flight
  BSTAGE(0, 0);
  ALOADA(0);
  ASTOREA(0);
  ALOADB(BK);          // chunk 1, survives the barrier (newest vmem ops)
  __syncthreads();

#pragma unroll
  for (int j = 0; j < NJ; ++j) {
    const int cur = j & 1;
    if (j + 1 < NJ) BSTAGE(cur ^ 1, (j + 1) * BK);
    if ((j & 1) == 0) { if (j + 2 < NJ) ALOADA((j + 2) * BK); }
    else              { if (j + 2 < NJ) ALOADB((j + 2) * BK); }
    COMPUTE1(cur);
    if ((j & 1) == 0) { if (j + 1 < NJ) ASTOREB(cur ^ 1); }
    else              { if (j + 1 < NJ) ASTOREA(cur ^ 1); }
    __syncthreads();
  }

  float* Yo = Ypart + (size_t)z * NROWS * KSEL;
#pragma unroll
  for (int i = 0; i < 4; ++i) {
    const int row_local = half * 64 + i * 16 + (lane & 15);
    if (row_local < cnt) {
#pragma unroll
      for (int j = 0; j < 4; ++j) {
        const int col = wave * 64 + j * 16 + (lane >> 4) * 4;
        *reinterpret_cast<f32x4_t*>(&Yo[(size_t)(start + row_local) * KSEL + col]) =
            acc[i][j];
      }
    }
  }
}

// ---- combine split-K partials (8) -> Ysel bf16 [8192, 256] ----
__global__ __launch_bounds__(256) void combine(const float* __restrict__ Yp,
                                               unsigned short* __restrict__ Ysel) {
  const int total = NROWS * KSEL / 4;
  const size_t stride = (size_t)NROWS * KSEL;
  for (int i = blockIdx.x * blockDim.x + threadIdx.x; i < total;
       i += gridDim.x * blockDim.x) {
    float4 s = ((const float4*)Yp)[i];
#pragma unroll
    for (int z = 1; z < KSPLIT; ++z) {
      float4 v = ((const float4*)(Yp + stride * z))[i];
      s.x += v.x; s.y += v.y; s.z += v.z; s.w += v.w;
    }
    ushort4 o;
    o.x = f2bf(s.x); o.y = f2bf(s.y); o.z = f2bf(s.z); o.w = f2bf(s.w);
    ((ushort4*)Ysel)[i] = o;
  }
}

// ---- GEMM2: 512 threads, tile 128 rows x 256 cols, BK=32, 2-phase dbuf,
// XCD-pinned (round-15 proven, byte-identical).
// out[perm[i],:] = base[perm[i],:] + Ysel[i,:] @ Wsel^T ----
__global__ __launch_bounds__(512) void gemm2(
    const unsigned short* __restrict__ Ysel,   // [8192, 256] bf16
    const unsigned short* __restrict__ Wb,     // [4096,1024] bf16
    const int* __restrict__ perm,
    const int* __restrict__ tiles, const int* __restrict__ n_tiles,
    const float* __restrict__ base, float* __restrict__ out) {
  __shared__ __attribute__((aligned(16))) __bf16 As[2][128 * BK];  // 8KB/buf
  __shared__ __attribute__((aligned(16))) __bf16 Bs[2][256 * BK];  // 16KB/buf

  const int bid  = blockIdx.x + blockIdx.y * gridDim.x;
  const int xcd  = bid & 7;
  const int j_   = bid >> 3;           // [0,256)
  const int tile = j_ & 127;
  const int npnl = xcd * 2 + (j_ >> 7);  // [0,16)

  if (tile >= *n_tiles) return;
  const int start = tiles[3 * tile + 0];
  const int cnt   = tiles[3 * tile + 1];
  const int bkt   = tiles[3 * tile + 2];
  const int s0    = bkt >> 3, s1 = bkt & 7;
  const int n0    = npnl * 256;

  const int tid  = threadIdx.x;        // 0..511
  const int lane = tid & 63;
  const int wave = tid >> 6;           // 0..7
  const int wm   = wave >> 2;          // 0..1
  const int wn   = wave & 3;           // 0..3

  const int arow = tid >> 2;           // 0..127
  const int akel = (tid & 3) * 8;
  const int arc  = arow < cnt ? arow : 0;
  const unsigned short* aptr = Ysel + (size_t)(start + arc) * KSEL + akel;

  const unsigned short* bptr[2];
#pragma unroll
  for (int q = 0; q < 2; ++q) {
    const int sidx = q * 512 + tid;
    const int brow = sidx >> 2;        // 0..255
    bptr[q] = Wb + (size_t)(n0 + brow) * PROJ_DIM + (sidx & 3) * 8;
  }

#define STAGE2(buf, kt)                                                        \
  {                                                                            \
    const int sp   = ((kt) < 128) ? s0 : s1;                                   \
    const int coff = sp * PARTSZ + ((kt) & 127);                               \
    stage16(aptr + (kt), (char*)&As[buf][0] + tid * 16);                       \
    stage16(bptr[0] + coff, (char*)&Bs[buf][0] + tid * 16);                    \
    stage16(bptr[1] + coff, (char*)&Bs[buf][0] + 8192 + tid * 16);             \
  }

  f32x4_t acc[4][4] = {};

  STAGE2(0, 0);
  __syncthreads();
  int cur = 0;
#pragma unroll
  for (int kt = 0; kt < KSEL; kt += BK) {
    if (kt + BK < KSEL) STAGE2(cur ^ 1, kt + BK);
    bf16x8_t af[4], bv[4];
#pragma unroll
    for (int i = 0; i < 4; ++i)
      af[i] = *reinterpret_cast<const bf16x8_t*>(
          &As[cur][(wm * 64 + i * 16 + (lane & 15)) * BK + (lane >> 4) * 8]);
#pragma unroll
    for (int j = 0; j < 4; ++j)
      bv[j] = *reinterpret_cast<const bf16x8_t*>(
          &Bs[cur][(wn * 64 + j * 16 + (lane & 15)) * BK + (lane >> 4) * 8]);
    // swapped operands -> lane holds 4 consecutive output cols of one row
#pragma unroll
    for (int i = 0; i < 4; ++i)
#pragma unroll
      for (int j = 0; j < 4; ++j)
        acc[i][j] = __builtin_amdgcn_mfma_f32_16x16x32_bf16(bv[j], af[i],
                                                            acc[i][j], 0, 0, 0);
    __syncthreads();
    cur ^= 1;
  }

#pragma unroll
  for (int i = 0; i < 4; ++i) {
    const int row_local = wm * 64 + i * 16 + (lane & 15);
    if (row_local < cnt) {
      const int grow = perm[start + row_local];
#pragma unroll
      for (int j = 0; j < 4; ++j) {
        const int col = n0 + wn * 64 + j * 16 + (lane >> 4) * 4;
        const size_t o = (size_t)grow * EMBED_DIM + col;
        f32x4_t b4 = *reinterpret_cast<const f32x4_t*>(&base[o]);
        *reinterpret_cast<f32x4_t*>(&out[o]) = acc[i][j] + b4;
      }
    }
  }
}

extern "C" void kernel_launch(void* const* d_in, const int* in_sizes, int n_in,
                              void* d_out, int out_size, void* d_ws, size_t ws_size,
                              hipStream_t stream) {
  const float* base   = (const float*)d_in[0];
  const float* source = (const float*)d_in[1];
  const int*   subs   = (const int*)d_in[2];
  const float* W      = (const float*)d_in[3];
  float* out = (float*)d_out;

  // d_out scratch (dead before gemm2 writes out):
  //   Ypart f32 [8][8192][256] @ 0   (64 MB; d_out is 128 MB)
  float* Ypart = (float*)d_out;

  // ws: Wb 8MB | WTb 8MB | Ysel 4MB | meta
  char* ws = (char*)d_ws;
  unsigned short* Wb   = (unsigned short*)(ws);
  unsigned short* WTb  = (unsigned short*)(ws + (8u << 20));
  unsigned short* Ysel = (unsigned short*)(ws + (16u << 20));
  char* meta = ws + (21u << 20);
  int* n_tiles = (int*)(meta);
  int* tiles   = (int*)(meta + 256);   // 128*3 ints
  int* perm    = (int*)(meta + 4096);  // 8192 ints

  k_bucket<<<1, 1024, 0, stream>>>(subs, tiles, n_tiles, perm);

  prep_w<<<dim3(PROJ_DIM / 32, EMBED_DIM / 32), 256, 0, stream>>>(W, Wb, WTb);

  gemm1<<<MAXTILES * 2 * KSPLIT, 256, 0, stream>>>(base, source, WTb, perm,
                                                   tiles, n_tiles, Ypart);
  combine<<<1024, 256, 0, stream>>>(Ypart, Ysel);

  gemm2<<<dim3(MAXTILES, EMBED_DIM / 256), 512, 0, stream>>>(Ysel, Wb, perm, tiles,
                                                             n_tiles, base, out);
}

// Round 18
// 201.314 us; speedup vs baseline: 1.1290x; 1.0679x over previous
//
#include <hip/hip_runtime.h>
#include <hip/hip_bf16.h>

#define EMBED_DIM 4096
#define PROJ_DIM  1024
#define NROWS     8192
#define NPART     8
#define PARTSZ    128
#define MAXTILES  128
#define KSPLIT    8
#define KCHUNK    512    // EMBED_DIM / KSPLIT
#define KSEL      256    // gathered columns per row
#define BK        32     // 64B LDS rows: bank-spread ds_read_b128
#define NJ        16     // K-steps per block in gemm1 (KCHUNK/BK)

typedef __bf16 bf16x8_t __attribute__((ext_vector_type(8)));
typedef float  f32x4_t  __attribute__((ext_vector_type(4)));
typedef unsigned short ushort8_t __attribute__((ext_vector_type(8)));

__device__ __forceinline__ unsigned short f2bf(float f) {
  unsigned u = __builtin_bit_cast(unsigned, f);
  u += 0x7fffu + ((u >> 16) & 1u);   // round-to-nearest-even
  return (unsigned short)(u >> 16);
}

__device__ __forceinline__ float bf2f(unsigned short u) {
  unsigned x = (unsigned)u << 16;
  return __builtin_bit_cast(float, x);
}

__device__ __forceinline__ void stage16(const void* g, void* l) {
  __builtin_amdgcn_global_load_lds(
      (const __attribute__((address_space(1))) unsigned int*)g,
      (__attribute__((address_space(3))) unsigned int*)l, 16, 0, 0);
}

// ---- Wb = bf16(W) [4096,1024]; WTb = bf16(W^T) [1024,4096] ----
__global__ __launch_bounds__(256) void prep_w(const float* __restrict__ W,
                                              unsigned short* __restrict__ Wb,
                                              unsigned short* __restrict__ WTb) {
  __shared__ float t[32][33];
  const int px = threadIdx.x & 31;
  const int ty = threadIdx.x >> 5;
  const int p0 = blockIdx.x * 32;
  const int d0 = blockIdx.y * 32;
#pragma unroll
  for (int i = 0; i < 32; i += 8) {
    float v = W[(size_t)(d0 + ty + i) * PROJ_DIM + p0 + px];
    t[ty + i][px] = v;
    Wb[(size_t)(d0 + ty + i) * PROJ_DIM + p0 + px] = f2bf(v);
  }
  __syncthreads();
#pragma unroll
  for (int i = 0; i < 32; i += 8) {
    WTb[(size_t)(p0 + ty + i) * EMBED_DIM + d0 + px] = f2bf(t[px][ty + i]);
  }
}

// ---- single-block bucketing: hist -> scan -> tile table -> scatter ----
__global__ __launch_bounds__(1024) void k_bucket(const int* __restrict__ subs,
                                                 int* __restrict__ tiles,
                                                 int* __restrict__ n_tiles,
                                                 int* __restrict__ perm) {
  __shared__ int h[64], off[64], cur[64];
  const int t = threadIdx.x;
  if (t < 64) h[t] = 0;
  __syncthreads();
  for (int r = t; r < NROWS; r += 1024)
    atomicAdd(&h[subs[2 * r] * NPART + subs[2 * r + 1]], 1);
  __syncthreads();
  if (t < 64) {  // threads 0..63 == wave 0
    int v = h[t], incl = v;
#pragma unroll
    for (int o = 1; o < 64; o <<= 1) { int n = __shfl_up(incl, o); if (t >= o) incl += n; }
    int excl = incl - v;
    off[t] = excl; cur[t] = 0;
    int tc = (v + 127) >> 7, tincl = tc;
#pragma unroll
    for (int o = 1; o < 64; o <<= 1) { int n = __shfl_up(tincl, o); if (t >= o) tincl += n; }
    int texcl = tincl - tc;
    for (int k = 0; k < tc; ++k) {
      tiles[3 * (texcl + k) + 0] = excl + k * 128;
      tiles[3 * (texcl + k) + 1] = min(128, v - k * 128);
      tiles[3 * (texcl + k) + 2] = t;
    }
    if (t == 63) *n_tiles = tincl;
  }
  __syncthreads();
  for (int r = t; r < NROWS; r += 1024) {
    int p = subs[2 * r] * NPART + subs[2 * r + 1];
    perm[off[p] + atomicAdd(&cur[p], 1)] = r;
  }
}

// ---- GEMM1 fused (delta in-register), XCD-pinned, 2-chunks-per-barrier.
// 4 LDS buffer pairs; super-iter sj stages chunks 2sj+2,2sj+3 into the idle
// pair while computing 2sj,2sj+1 -> 9 barrier drains instead of 17.
// bf16 partial output (halves Ypart traffic).
// Ypart[z][i, 0:256] = bf16( (source-base)[perm[i], z*512..] @ Wsel ) ----
__global__ __launch_bounds__(256) void gemm1(
    const float* __restrict__ base, const float* __restrict__ source,
    const unsigned short* __restrict__ WTb,    // [1024,4096] bf16
    const int* __restrict__ perm,
    const int* __restrict__ tiles, const int* __restrict__ n_tiles,
    unsigned short* __restrict__ Ypart) {      // [KSPLIT][8192][256] bf16
  __shared__ __attribute__((aligned(16))) __bf16 As[4][64 * BK];    // 16KB
  __shared__ __attribute__((aligned(16))) __bf16 Bs[4][256 * BK];   // 64KB

  const int bid  = blockIdx.x;         // [0,2048)
  const int z    = bid & 7;            // XCD-pinned K chunk
  const int th   = bid >> 3;           // [0,256)
  const int tile = th & 127;
  const int half = th >> 7;            // 0/1: which 64-row half of the tile
  if (tile >= *n_tiles) return;
  const int start = tiles[3 * tile + 0];
  const int cnt   = tiles[3 * tile + 1];
  if (half * 64 >= cnt) return;
  const int bkt   = tiles[3 * tile + 2];
  const int s0    = bkt >> 3, s1 = bkt & 7;
  const int kbase = z * KCHUNK;

  const int tid  = threadIdx.x;
  const int lane = tid & 63;
  const int wave = tid >> 6;           // 0..3 == column quarter (wm = 0)

  // A reg-stage slot: 64 rows x 4 k-groups of 8 = 256 slots, 1/thread
  const int at_row = tid >> 2;         // 0..63
  const int at_kg  = (tid & 3) * 8;    // 0/8/16/24
  const int arow_g = perm[start + min(half * 64 + at_row, cnt - 1)];
  const float* abase = base   + (size_t)arow_g * EMBED_DIM + kbase + at_kg;
  const float* asrc  = source + (size_t)arow_g * EMBED_DIM + kbase + at_kg;

  // B stage: 16 chunks of 16 rows (256 selected W-cols); 4 stage16/thread
  const unsigned short* bptr[4];
#pragma unroll
  for (int it = 0; it < 4; ++it) {
    const int r   = (it * 4 + wave) * 16 + (lane >> 2);   // 0..255
    const int sel = (r < 128) ? (s0 * PARTSZ + r) : (s1 * PARTSZ + r - 128);
    bptr[it] = WTb + (size_t)sel * EMBED_DIM + kbase + (lane & 3) * 8;
  }

  // two named register sets: set A = even chunk of the pair, set B = odd
  float4 abA0, abA1, asA0, asA1;
  float4 abB0, abB1, asB0, asB1;

#define ALOADA(kt)                                                          \
  { abA0 = *(const float4*)(abase + (kt));                                  \
    abA1 = *(const float4*)(abase + (kt) + 4);                              \
    asA0 = *(const float4*)(asrc + (kt));                                   \
    asA1 = *(const float4*)(asrc + (kt) + 4); }

#define ALOADB(kt)                                                          \
  { abB0 = *(const float4*)(abase + (kt));                                  \
    abB1 = *(const float4*)(abase + (kt) + 4);                              \
    asB0 = *(const float4*)(asrc + (kt));                                   \
    asB1 = *(const float4*)(asrc + (kt) + 4); }

#define ASTOREA(buf)                                                        \
  { ushort8_t o;                                                            \
    o[0] = f2bf(asA0.x - abA0.x); o[1] = f2bf(asA0.y - abA0.y);             \
    o[2] = f2bf(asA0.z - abA0.z); o[3] = f2bf(asA0.w - abA0.w);             \
    o[4] = f2bf(asA1.x - abA1.x); o[5] = f2bf(asA1.y - abA1.y);             \
    o[6] = f2bf(asA1.z - abA1.z); o[7] = f2bf(asA1.w - abA1.w);             \
    *(ushort8_t*)&As[buf][at_row * BK + at_kg] = o; }

#define ASTOREB(buf)                                                        \
  { ushort8_t o;                                                            \
    o[0] = f2bf(asB0.x - abB0.x); o[1] = f2bf(asB0.y - abB0.y);             \
    o[2] = f2bf(asB0.z - abB0.z); o[3] = f2bf(asB0.w - abB0.w);             \
    o[4] = f2bf(asB1.x - abB1.x); o[5] = f2bf(asB1.y - abB1.y);             \
    o[6] = f2bf(asB1.z - abB1.z); o[7] = f2bf(asB1.w - abB1.w);             \
    *(ushort8_t*)&As[buf][at_row * BK + at_kg] = o; }

#define BSTAGE(buf, kt)                                                     \
  {                                                                         \
    _Pragma("unroll") for (int it = 0; it < 4; ++it) {                      \
      const int c = it * 4 + wave;                                          \
      stage16(bptr[it] + (kt), (char*)&Bs[buf][0] + c * 1024);              \
    }                                                                       \
  }

#define COMPUTE1(buf)                                                       \
  {                                                                         \
    bf16x8_t af[4], bv[4];                                                  \
    _Pragma("unroll") for (int i = 0; i < 4; ++i)                           \
      af[i] = *reinterpret_cast<const bf16x8_t*>(                           \
          &As[buf][(i * 16 + (lane & 15)) * BK + (lane >> 4) * 8]);         \
    _Pragma("unroll") for (int j = 0; j < 4; ++j)                           \
      bv[j] = *reinterpret_cast<const bf16x8_t*>(                           \
          &Bs[buf][(wave * 64 + j * 16 + (lane & 15)) * BK + (lane >> 4) * 8]); \
    _Pragma("unroll") for (int i = 0; i < 4; ++i)                           \
      _Pragma("unroll") for (int j = 0; j < 4; ++j)                         \
        acc[i][j] = __builtin_amdgcn_mfma_f32_16x16x32_bf16(bv[j], af[i],   \
                                                            acc[i][j], 0, 0, 0); \
  }

  f32x4_t acc[4][4] = {};

  // prologue: chunks 0,1 staged into buffer pair {0,1}
  BSTAGE(0, 0);
  BSTAGE(1, BK);
  ALOADA(0);
  ALOADB(BK);
  ASTOREA(0);
  ASTOREB(1);
  __syncthreads();

#pragma unroll
  for (int sj = 0; sj < NJ / 2; ++sj) {   // 8 super-iters, 2 chunks each
    const int c0 = (2 * sj) & 3;          // buffer of chunk 2sj
    const int c1 = (2 * sj + 1) & 3;      // buffer of chunk 2sj+1
    const int n0b = (2 * sj + 2) & 3;     // idle pair (written this iter)
    const int n1b = (2 * sj + 3) & 3;
    if (sj + 1 < NJ / 2) {
      BSTAGE(n0b, (2 * sj + 2) * BK);
      BSTAGE(n1b, (2 * sj + 3) * BK);
      ALOADA((2 * sj + 2) * BK);
      ALOADB((2 * sj + 3) * BK);
    }
    COMPUTE1(c0);
    COMPUTE1(c1);
    if (sj + 1 < NJ / 2) {
      ASTOREA(n0b);
      ASTOREB(n1b);
    }
    __syncthreads();
  }

  unsigned short* Yo = Ypart + (size_t)z * NROWS * KSEL;
#pragma unroll
  for (int i = 0; i < 4; ++i) {
    const int row_local = half * 64 + i * 16 + (lane & 15);
    if (row_local < cnt) {
#pragma unroll
      for (int j = 0; j < 4; ++j) {
        const int col = wave * 64 + j * 16 + (lane >> 4) * 4;
        ushort4 o;
        o.x = f2bf(acc[i][j][0]); o.y = f2bf(acc[i][j][1]);
        o.z = f2bf(acc[i][j][2]); o.w = f2bf(acc[i][j][3]);
        *reinterpret_cast<ushort4*>(
            &Yo[(size_t)(start + row_local) * KSEL + col]) = o;
      }
    }
  }
}

// ---- combine bf16 split-K partials (8) -> Ysel bf16 [8192, 256] ----
__global__ __launch_bounds__(256) void combine(const unsigned short* __restrict__ Yp,
                                               unsigned short* __restrict__ Ysel) {
  const int total = NROWS * KSEL / 4;
  const int stride4 = NROWS * KSEL / 4;   // in ushort4 units
  for (int i = blockIdx.x * blockDim.x + threadIdx.x; i < total;
       i += gridDim.x * blockDim.x) {
    float sx = 0.f, sy = 0.f, sz = 0.f, sw = 0.f;
#pragma unroll
    for (int z = 0; z < KSPLIT; ++z) {
      ushort4 v = ((const ushort4*)Yp)[(size_t)z * stride4 + i];
      sx += bf2f(v.x); sy += bf2f(v.y); sz += bf2f(v.z); sw += bf2f(v.w);
    }
    ushort4 o;
    o.x = f2bf(sx); o.y = f2bf(sy); o.z = f2bf(sz); o.w = f2bf(sw);
    ((ushort4*)Ysel)[i] = o;
  }
}

// ---- GEMM2: 512 threads, tile 128 rows x 256 cols, BK=32, 2-phase dbuf,
// XCD-pinned (round-15 proven, byte-identical).
// out[perm[i],:] = base[perm[i],:] + Ysel[i,:] @ Wsel^T ----
__global__ __launch_bounds__(512) void gemm2(
    const unsigned short* __restrict__ Ysel,   // [8192, 256] bf16
    const unsigned short* __restrict__ Wb,     // [4096,1024] bf16
    const int* __restrict__ perm,
    const int* __restrict__ tiles, const int* __restrict__ n_tiles,
    const float* __restrict__ base, float* __restrict__ out) {
  __shared__ __attribute__((aligned(16))) __bf16 As[2][128 * BK];  // 8KB/buf
  __shared__ __attribute__((aligned(16))) __bf16 Bs[2][256 * BK];  // 16KB/buf

  const int bid  = blockIdx.x + blockIdx.y * gridDim.x;
  const int xcd  = bid & 7;
  const int j_   = bid >> 3;           // [0,256)
  const int tile = j_ & 127;
  const int npnl = xcd * 2 + (j_ >> 7);  // [0,16)

  if (tile >= *n_tiles) return;
  const int start = tiles[3 * tile + 0];
  const int cnt   = tiles[3 * tile + 1];
  const int bkt   = tiles[3 * tile + 2];
  const int s0    = bkt >> 3, s1 = bkt & 7;
  const int n0    = npnl * 256;

  const int tid  = threadIdx.x;        // 0..511
  const int lane = tid & 63;
  const int wave = tid >> 6;           // 0..7
  const int wm   = wave >> 2;          // 0..1
  const int wn   = wave & 3;           // 0..3

  const int arow = tid >> 2;           // 0..127
  const int akel = (tid & 3) * 8;
  const int arc  = arow < cnt ? arow : 0;
  const unsigned short* aptr = Ysel + (size_t)(start + arc) * KSEL + akel;

  const unsigned short* bptr[2];
#pragma unroll
  for (int q = 0; q < 2; ++q) {
    const int sidx = q * 512 + tid;
    const int brow = sidx >> 2;        // 0..255
    bptr[q] = Wb + (size_t)(n0 + brow) * PROJ_DIM + (sidx & 3) * 8;
  }

#define STAGE2(buf, kt)                                                        \
  {                                                                            \
    const int sp   = ((kt) < 128) ? s0 : s1;                                   \
    const int coff = sp * PARTSZ + ((kt) & 127);                               \
    stage16(aptr + (kt), (char*)&As[buf][0] + tid * 16);                       \
    stage16(bptr[0] + coff, (char*)&Bs[buf][0] + tid * 16);                    \
    stage16(bptr[1] + coff, (char*)&Bs[buf][0] + 8192 + tid * 16);             \
  }

  f32x4_t acc[4][4] = {};

  STAGE2(0, 0);
  __syncthreads();
  int cur = 0;
#pragma unroll
  for (int kt = 0; kt < KSEL; kt += BK) {
    if (kt + BK < KSEL) STAGE2(cur ^ 1, kt + BK);
    bf16x8_t af[4], bv[4];
#pragma unroll
    for (int i = 0; i < 4; ++i)
      af[i] = *reinterpret_cast<const bf16x8_t*>(
          &As[cur][(wm * 64 + i * 16 + (lane & 15)) * BK + (lane >> 4) * 8]);
#pragma unroll
    for (int j = 0; j < 4; ++j)
      bv[j] = *reinterpret_cast<const bf16x8_t*>(
          &Bs[cur][(wn * 64 + j * 16 + (lane & 15)) * BK + (lane >> 4) * 8]);
    // swapped operands -> lane holds 4 consecutive output cols of one row
#pragma unroll
    for (int i = 0; i < 4; ++i)
#pragma unroll
      for (int j = 0; j < 4; ++j)
        acc[i][j] = __builtin_amdgcn_mfma_f32_16x16x32_bf16(bv[j], af[i],
                                                            acc[i][j], 0, 0, 0);
    __syncthreads();
    cur ^= 1;
  }

#pragma unroll
  for (int i = 0; i < 4; ++i) {
    const int row_local = wm * 64 + i * 16 + (lane & 15);
    if (row_local < cnt) {
      const int grow = perm[start + row_local];
#pragma unroll
      for (int j = 0; j < 4; ++j) {
        const int col = n0 + wn * 64 + j * 16 + (lane >> 4) * 4;
        const size_t o = (size_t)grow * EMBED_DIM + col;
        f32x4_t b4 = *reinterpret_cast<const f32x4_t*>(&base[o]);
        *reinterpret_cast<f32x4_t*>(&out[o]) = acc[i][j] + b4;
      }
    }
  }
}

extern "C" void kernel_launch(void* const* d_in, const int* in_sizes, int n_in,
                              void* d_out, int out_size, void* d_ws, size_t ws_size,
                              hipStream_t stream) {
  const float* base   = (const float*)d_in[0];
  const float* source = (const float*)d_in[1];
  const int*   subs   = (const int*)d_in[2];
  const float* W      = (const float*)d_in[3];
  float* out = (float*)d_out;

  // d_out scratch (dead before gemm2 writes out):
  //   Ypart bf16 [8][8192][256] @ 0   (32 MB; d_out is 128 MB)
  unsigned short* Ypart = (unsigned short*)d_out;

  // ws: Wb 8MB | WTb 8MB | Ysel 4MB | meta
  char* ws = (char*)d_ws;
  unsigned short* Wb   = (unsigned short*)(ws);
  unsigned short* WTb  = (unsigned short*)(ws + (8u << 20));
  unsigned short* Ysel = (unsigned short*)(ws + (16u << 20));
  char* meta = ws + (21u << 20);
  int* n_tiles = (int*)(meta);
  int* tiles   = (int*)(meta + 256);   // 128*3 ints
  int* perm    = (int*)(meta + 4096);  // 8192 ints

  k_bucket<<<1, 1024, 0, stream>>>(subs, tiles, n_tiles, perm);

  prep_w<<<dim3(PROJ_DIM / 32, EMBED_DIM / 32), 256, 0, stream>>>(W, Wb, WTb);

  gemm1<<<MAXTILES * 2 * KSPLIT, 256, 0, stream>>>(base, source, WTb, perm,
                                                   tiles, n_tiles, Ypart);
  combine<<<1024, 256, 0, stream>>>(Ypart, Ysel);

  gemm2<<<dim3(MAXTILES, EMBED_DIM / 256), 512, 0, stream>>>(Ysel, Wb, perm, tiles,
                                                             n_tiles, base, out);
}